// Round 3
// baseline (274.680 us; speedup 1.0000x reference)
//
#include <hip/hip_runtime.h>
#include <stdint.h>

// SNN readout: h = inputs @ W^T (bf16 MFMA), then chunked parallel linear scan.
//   flt_t = ALPHA*flt_{t-1} + h_t ;  out_t = BETA*out_{t-1} + flt_{t-1}
// R3 GEMM: W-quarter resident in LDS (bf16, XOR-swizzled, 64KB), A streamed
// DIRECTLY global->VGPR (no LDS, no barriers in K-loop -> compiler free to
// pipeline with fine-grained vmcnt). fp32->bf16 conversion in-register.

#define ALPHA 0.95f
#define BETA  0.9f

constexpr int Bdim = 64, T = 1000, Idim = 512, Odim = 256;
constexpr int M = Bdim * T;         // 64000 rows
constexpr int C = 40, L = 25;       // T = C*L
constexpr int BO = Bdim * Odim;     // 16384 independent sequences

typedef short bf16x8 __attribute__((ext_vector_type(8)));   // 8 bf16 (4 VGPRs)
typedef float f32x4  __attribute__((ext_vector_type(4)));

// round-to-nearest-even fp32 -> bf16, packed pair into one u32
__device__ inline uint32_t pk_bf16(float a, float b) {
  union { float f; uint32_t u; } x, y; x.f = a; y.f = b;
  uint32_t lo = (x.u + 0x7FFFu + ((x.u >> 16) & 1u)) >> 16;
  uint32_t hi = (y.u + 0x7FFFu + ((y.u >> 16) & 1u)) & 0xFFFF0000u;
  return lo | hi;
}
__device__ inline uint16_t f2bf(float a) {
  union { float f; uint32_t u; } x; x.f = a;
  return (uint16_t)((x.u + 0x7FFFu + ((x.u >> 16) & 1u)) >> 16);
}
__device__ inline float bf2f(uint16_t h) {
  union { uint32_t u; float f; } x; x.u = ((uint32_t)h) << 16;
  return x.f;
}

// ---------------- GEMM: H[m][n] = sum_k A[m][k] * W[n][k], bf16 MFMA ----------------
// grid(4, 250): x = N-quarter (consecutive blocks share the A tile -> L2/LLC hot),
// y = 256-row M-tile. Block: 4 waves, each wave does 64(M) x 64(N).
__global__ __launch_bounds__(256, 2) void gemm_h(const float* __restrict__ A,
                                                 const float* __restrict__ W,
                                                 uint16_t* __restrict__ H) {
  __shared__ uint16_t Wl[64 * 512];   // 64KB: rows n (64), 512 k, 16B-chunk c at (c ^ (n&7))

  const int tid  = threadIdx.x;
  const int lane = tid & 63;
  const int wave = tid >> 6;
  const int l15  = lane & 15;
  const int quad = lane >> 4;
  const int cn   = blockIdx.x * 64;     // N-quarter
  const int rm   = blockIdx.y * 256;    // M-tile

  // ---- prologue: convert W quarter fp32 -> bf16 into swizzled LDS ----
  {
    const int r  = tid >> 2;            // 0..63 (row within quarter)
    const int cb = (tid & 3) * 16;      // 16 chunks of 8 elems each
    const float* wr = W + (size_t)(cn + r) * Idim;
#pragma unroll
    for (int i = 0; i < 16; ++i) {
      int c = cb + i;
      float4 lo = *(const float4*)(wr + c * 8);
      float4 hi = *(const float4*)(wr + c * 8 + 4);
      *(uint4*)&Wl[r * 512 + ((c ^ (r & 7)) * 8)] =
          make_uint4(pk_bf16(lo.x, lo.y), pk_bf16(lo.z, lo.w),
                     pk_bf16(hi.x, hi.y), pk_bf16(hi.z, hi.w));
    }
  }
  __syncthreads();   // the only barrier; W is read-only afterwards

  // A-fragment base pointers: lane (l15) owns row (rm + wave*64 + mt*16 + l15),
  // k-octet quad*8 (A-operand layout: m = lane&15, k = quad*8 + j)
  const float* ar[4];
#pragma unroll
  for (int mt = 0; mt < 4; ++mt)
    ar[mt] = A + (size_t)(rm + wave * 64 + mt * 16 + l15) * Idim + quad * 8;

  f32x4 acc[4][4] = {};

  float4 cur[4][2];
#pragma unroll
  for (int mt = 0; mt < 4; ++mt) {
    cur[mt][0] = *(const float4*)(ar[mt]);
    cur[mt][1] = *(const float4*)(ar[mt] + 4);
  }

#pragma unroll
  for (int ks = 0; ks < 16; ++ks) {
    float4 nxt[4][2];
    if (ks < 15) {
#pragma unroll
      for (int mt = 0; mt < 4; ++mt) {
        nxt[mt][0] = *(const float4*)(ar[mt] + (ks + 1) * 32);
        nxt[mt][1] = *(const float4*)(ar[mt] + (ks + 1) * 32 + 4);
      }
    }
    // B fragments from resident LDS (conflict-free via XOR swizzle)
    bf16x8 bfr[4];
#pragma unroll
    for (int nt = 0; nt < 4; ++nt)
      bfr[nt] = *(const bf16x8*)&Wl[(nt * 16 + l15) * 512 + (((ks * 4 + quad) ^ (l15 & 7)) * 8)];
    // convert current A k-slice fp32 -> bf16
    bf16x8 af[4];
#pragma unroll
    for (int mt = 0; mt < 4; ++mt) {
      union { uint4 u; bf16x8 v; } t;
      t.u = make_uint4(pk_bf16(cur[mt][0].x, cur[mt][0].y), pk_bf16(cur[mt][0].z, cur[mt][0].w),
                       pk_bf16(cur[mt][1].x, cur[mt][1].y), pk_bf16(cur[mt][1].z, cur[mt][1].w));
      af[mt] = t.v;
    }
#pragma unroll
    for (int mt = 0; mt < 4; ++mt)
#pragma unroll
      for (int nt = 0; nt < 4; ++nt)
        acc[mt][nt] = __builtin_amdgcn_mfma_f32_16x16x32_bf16(af[mt], bfr[nt], acc[mt][nt], 0, 0, 0);
    if (ks < 15) {
#pragma unroll
      for (int mt = 0; mt < 4; ++mt) { cur[mt][0] = nxt[mt][0]; cur[mt][1] = nxt[mt][1]; }
    }
  }

  // epilogue: C/D layout col = lane&15, row = quad*4 + reg
#pragma unroll
  for (int mt = 0; mt < 4; ++mt)
#pragma unroll
    for (int nt = 0; nt < 4; ++nt)
#pragma unroll
      for (int r = 0; r < 4; ++r) {
        int gm = rm + wave * 64 + mt * 16 + quad * 4 + r;
        int gn = cn + nt * 16 + l15;
        H[(size_t)gm * Odim + gn] = f2bf(acc[mt][nt][r]);
      }
}

// ---------------- pass 1: per-chunk local scan (zero init) -> (lf, lu) --------------
__global__ __launch_bounds__(256) void scan_local(const uint16_t* __restrict__ H,
                                                  float2* __restrict__ St) {
  const int pair = blockIdx.x * 4 + (threadIdx.x >> 6);
  const int b = pair / C, c = pair % C;
  const int lane = threadIdx.x & 63;
  const ushort4* hp = (const ushort4*)(H + (size_t)(b * T + c * L) * Odim) + lane;
  float f[4] = {}, u[4] = {};
#pragma unroll
  for (int j = 0; j < L; ++j) {
    ushort4 hv = hp[j * 64];
    float h0 = bf2f(hv.x), h1 = bf2f(hv.y), h2 = bf2f(hv.z), h3 = bf2f(hv.w);
    float n0 = BETA * u[0] + f[0]; f[0] = ALPHA * f[0] + h0; u[0] = n0;
    float n1 = BETA * u[1] + f[1]; f[1] = ALPHA * f[1] + h1; u[1] = n1;
    float n2 = BETA * u[2] + f[2]; f[2] = ALPHA * f[2] + h2; u[2] = n2;
    float n3 = BETA * u[3] + f[3]; f[3] = ALPHA * f[3] + h3; u[3] = n3;
  }
  float2* sp = &St[(size_t)c * BO + b * Odim + lane * 4];
#pragma unroll
  for (int i = 0; i < 4; ++i) sp[i] = make_float2(f[i], u[i]);
}

// ---------------- pass 2: sequential combine over the C chunk states ----------------
constexpr double dpow(double x, int n) { double r = 1.0; for (int i = 0; i < n; ++i) r *= x; return r; }

__global__ __launch_bounds__(256) void scan_combine(const float2* __restrict__ St,
                                                    float2* __restrict__ Init) {
  constexpr float AL = (float)dpow(0.95, L);
  constexpr float BL = (float)dpow(0.90, L);
  constexpr float WL = (float)((dpow(0.95, L) - dpow(0.90, L)) / (0.95 - 0.90));
  const int i = blockIdx.x * 256 + threadIdx.x;   // over B*O
  float f = 0.f, u = 0.f;
#pragma unroll
  for (int c = 0; c < C; ++c) {
    Init[(size_t)c * BO + i] = make_float2(f, u);
    float2 s = St[(size_t)c * BO + i];
    float nf = AL * f + s.x;
    float nu = BL * u + WL * f + s.y;
    f = nf; u = nu;
  }
}

// ---------------- pass 3: final scan with chunk-init, write outputs -----------------
__global__ __launch_bounds__(256) void scan_final(const uint16_t* __restrict__ H,
                                                  const float2* __restrict__ Init,
                                                  float* __restrict__ Out) {
  const int pair = blockIdx.x * 4 + (threadIdx.x >> 6);
  const int b = pair / C, c = pair % C;
  const int lane = threadIdx.x & 63;
  const size_t base = (size_t)(b * T + c * L) * Odim;
  const ushort4* hp = (const ushort4*)(H + base) + lane;
  float4* op = (float4*)(Out + base) + lane;
  const float2* sp = &Init[(size_t)c * BO + b * Odim + lane * 4];
  float f[4], u[4];
#pragma unroll
  for (int i = 0; i < 4; ++i) { float2 s = sp[i]; f[i] = s.x; u[i] = s.y; }
#pragma unroll
  for (int j = 0; j < L; ++j) {
    ushort4 hv = hp[j * 64];
    float h0 = bf2f(hv.x), h1 = bf2f(hv.y), h2 = bf2f(hv.z), h3 = bf2f(hv.w);
    float4 o4;
    o4.x = BETA * u[0] + f[0]; f[0] = ALPHA * f[0] + h0; u[0] = o4.x;
    o4.y = BETA * u[1] + f[1]; f[1] = ALPHA * f[1] + h1; u[1] = o4.y;
    o4.z = BETA * u[2] + f[2]; f[2] = ALPHA * f[2] + h2; u[2] = o4.z;
    o4.w = BETA * u[3] + f[3]; f[3] = ALPHA * f[3] + h3; u[3] = o4.w;
    op[j * 64] = o4;
  }
}

extern "C" void kernel_launch(void* const* d_in, const int* in_sizes, int n_in,
                              void* d_out, int out_size, void* d_ws, size_t ws_size,
                              hipStream_t stream) {
  const float* A = (const float*)d_in[0];   // (B, T, I) fp32
  const float* W = (const float*)d_in[1];   // (O, I) fp32
  float* Out = (float*)d_out;               // (B, T, O) fp32

  // workspace: H (bf16, M*O = 32.8MB) | St (C*BO float2, 5.2MB) | Init (5.2MB)
  uint16_t* H = (uint16_t*)d_ws;
  const size_t hbytes = (size_t)M * Odim * sizeof(uint16_t);
  float2* St   = (float2*)((char*)d_ws + hbytes);
  float2* Init = St + (size_t)C * BO;

  gemm_h<<<dim3(Odim / 64, M / 256), 256, 0, stream>>>(A, W, H);
  scan_local<<<Bdim * C / 4, 256, 0, stream>>>(H, St);
  scan_combine<<<BO / 256, 256, 0, stream>>>(St, Init);
  scan_final<<<Bdim * C / 4, 256, 0, stream>>>(H, Init, Out);
}

// Round 4
// 247.222 us; speedup vs baseline: 1.1111x; 1.1111x over previous
//
#include <hip/hip_runtime.h>
#include <hip/hip_bf16.h>
#include <stdint.h>

// SNN readout: h = inputs @ W^T (bf16 MFMA), then linear scan over T.
//   flt_t = ALPHA*flt_{t-1} + h_t ;  out_t = BETA*out_{t-1} + flt_{t-1}
// R4: (1) tiny W fp32->bf16 convert; (2) GEMM 64x256 tile (full N -> A read
// once), global_load_lds(16B) async staging of fp32-A + bf16-W, XOR-swizzled
// via global addresses, cvt_pk at fragment read; (3) whole scan fused into
// ONE kernel (local scans -> in-LDS combine -> final scan), C=40 L=25.

#define ALPHA 0.95f
#define BETA  0.9f

constexpr int Bdim = 64, T = 1000, Idim = 512, Odim = 256;
constexpr int M = Bdim * T;         // 64000 rows
constexpr int C = 40, L = 25;       // T = C*L

typedef short bf16x8 __attribute__((ext_vector_type(8)));
typedef float f32x4  __attribute__((ext_vector_type(4)));

__device__ inline uint32_t pk_bf16(float a, float b) {   // RNE pack
  union { float f; uint32_t u; } x, y; x.f = a; y.f = b;
  uint32_t lo = (x.u + 0x7FFFu + ((x.u >> 16) & 1u)) >> 16;
  uint32_t hi = (y.u + 0x7FFFu + ((y.u >> 16) & 1u)) & 0xFFFF0000u;
  return lo | hi;
}
__device__ inline uint16_t f2bf(float a) {
  union { float f; uint32_t u; } x; x.f = a;
  return (uint16_t)((x.u + 0x7FFFu + ((x.u >> 16) & 1u)) >> 16);
}
__device__ inline float bf2f(uint16_t h) {
  union { uint32_t u; float f; } x; x.u = ((uint32_t)h) << 16;
  return x.f;
}

// async 16B global->LDS (wave-uniform LDS base + lane*16)
#define GLD16(g, l) __builtin_amdgcn_global_load_lds(                         \
    (const __attribute__((address_space(1))) uint32_t*)(g),                   \
    (__attribute__((address_space(3))) uint32_t*)(l), 16, 0, 0)

// pack 8 fp32 (k-order) -> bf16x8 fragment via HW v_cvt_pk_bf16_f32
__device__ inline bf16x8 cvt8(float4 x0, float4 x1) {
  union { __hip_bfloat162 h[4]; bf16x8 v; } r;
  r.h[0] = __float22bfloat162_rn(make_float2(x0.x, x0.y));
  r.h[1] = __float22bfloat162_rn(make_float2(x0.z, x0.w));
  r.h[2] = __float22bfloat162_rn(make_float2(x1.x, x1.y));
  r.h[3] = __float22bfloat162_rn(make_float2(x1.z, x1.w));
  return r.v;
}

// -------- K0: W fp32 -> bf16 (RNE), 131072 elems --------
__global__ __launch_bounds__(256) void wconv(const float* __restrict__ W,
                                             uint16_t* __restrict__ Wbf) {
  int i = (blockIdx.x * 256 + threadIdx.x) * 8;
  float4 a = *(const float4*)(W + i);
  float4 b = *(const float4*)(W + i + 4);
  *(uint4*)(Wbf + i) = make_uint4(pk_bf16(a.x, a.y), pk_bf16(a.z, a.w),
                                  pk_bf16(b.x, b.y), pk_bf16(b.z, b.w));
}

// -------- K1: GEMM H[m][n] = sum_k A[m][k]*W[n][k] --------
// grid 1000 (M/64). Block: 64x256 tile, 4 waves (wave w -> n-range w*64).
// LDS: As = fp32 64x32 (128B rows, 16B chunk at slot kc^(row&7));
//      Bs = bf16 256x32 (64B rows, 16B chunk at slot kc^(row&3)).
__global__ __launch_bounds__(256) void gemm_h(const float* __restrict__ A,
                                              const uint16_t* __restrict__ Wbf,
                                              uint16_t* __restrict__ H) {
  __shared__ float    As[64 * 32];
  __shared__ uint16_t Bs[256 * 32];

  const int tid  = threadIdx.x;
  const int lane = tid & 63;
  const int w    = tid >> 6;
  const int l15  = lane & 15;
  const int quad = lane >> 4;
  const int rm   = blockIdx.x * 64;

  // staging address components (per-lane)
  const int ar = w * 8 + (lane >> 3);                 // + p*32 -> A row
  const int akc = (lane & 7) ^ ((lane >> 3) & 7);     // slot^(row&7)
  const int br = w * 16 + (lane >> 2);                // + p*64 -> B row
  const int bkc = (lane & 3) ^ ((lane >> 2) & 3);     // slot^(row&3)

  const float*    ag0 = A   + (size_t)(rm + ar) * Idim + akc * 4;        // p=0
  const float*    ag1 = A   + (size_t)(rm + 32 + ar) * Idim + akc * 4;   // p=1
  const uint16_t* bg[4];
#pragma unroll
  for (int p = 0; p < 4; ++p) bg[p] = Wbf + (size_t)(p * 64 + br) * Idim + bkc * 8;

  char* al0 = (char*)As + w * 1024;            // p=0 window
  char* al1 = (char*)As + 4096 + w * 1024;     // p=1
  char* bl[4];
#pragma unroll
  for (int p = 0; p < 4; ++p) bl[p] = (char*)Bs + p * 4096 + w * 1024;

  // fragment LDS offsets
  int aoff0[4], aoff1[4], boff[4];
#pragma unroll
  for (int t = 0; t < 4; ++t) {
    int m = t * 16 + l15;
    aoff0[t] = m * 32 + (((2 * quad)     ^ (m & 7)) * 4);
    aoff1[t] = m * 32 + (((2 * quad + 1) ^ (m & 7)) * 4);
    int n = w * 64 + t * 16 + l15;
    boff[t] = n * 32 + ((quad ^ (n & 3)) * 8);
  }

  f32x4 acc[4][4] = {};

  for (int k0 = 0; k0 < Idim; k0 += 32) {
    __syncthreads();                       // prev iter's ds_reads done
    GLD16(ag0 + k0, al0);
    GLD16(ag1 + k0, al1);
#pragma unroll
    for (int p = 0; p < 4; ++p) GLD16(bg[p] + k0, bl[p]);
    __syncthreads();                       // vmcnt(0) drain + barrier

    bf16x8 af[4], bfr[4];
#pragma unroll
    for (int t = 0; t < 4; ++t) {
      float4 x0 = *(const float4*)&As[aoff0[t]];
      float4 x1 = *(const float4*)&As[aoff1[t]];
      af[t] = cvt8(x0, x1);
    }
#pragma unroll
    for (int t = 0; t < 4; ++t) bfr[t] = *(const bf16x8*)&Bs[boff[t]];
#pragma unroll
    for (int mt = 0; mt < 4; ++mt)
#pragma unroll
      for (int nt = 0; nt < 4; ++nt)
        acc[mt][nt] = __builtin_amdgcn_mfma_f32_16x16x32_bf16(af[mt], bfr[nt], acc[mt][nt], 0, 0, 0);
  }

  // epilogue: C/D layout col = lane&15, row = quad*4 + reg
#pragma unroll
  for (int mt = 0; mt < 4; ++mt)
#pragma unroll
    for (int nt = 0; nt < 4; ++nt)
#pragma unroll
      for (int r = 0; r < 4; ++r) {
        int gm = rm + mt * 16 + quad * 4 + r;
        int gn = w * 64 + nt * 16 + l15;
        H[(size_t)gm * Odim + gn] = f2bf(acc[mt][nt][r]);
      }
}

// -------- K2: whole scan in one kernel --------
// grid 256 = (b, og): block owns 64 o's, all T. 640 thr: c = tid>>4 (40),
// ol = tid&15 (4 o's each). Phase1 local scans -> St(LDS); phase2 in-LDS
// combine (threads 0..63); phase3 final scan writes Out.
constexpr double dpow(double x, int n) { double r = 1.0; for (int i = 0; i < n; ++i) r *= x; return r; }

__global__ __launch_bounds__(640) void scan_all(const uint16_t* __restrict__ H,
                                                float* __restrict__ Out) {
  constexpr float AL = (float)dpow(0.95, L);
  constexpr float BL = (float)dpow(0.90, L);
  constexpr float WL = (float)((dpow(0.95, L) - dpow(0.90, L)) / (0.95 - 0.90));
  __shared__ float2 St[C][64];

  const int b  = blockIdx.x >> 2;
  const int og = blockIdx.x & 3;
  const int tid = threadIdx.x;
  const int c  = tid >> 4;
  const int ol = tid & 15;

  const size_t base = ((size_t)b * T + c * L) * Odim + og * 64 + ol * 4;
  const ushort4* hp = (const ushort4*)(H + base);

  // phase 1: local scan, zero init
  {
    float f[4] = {}, u[4] = {};
#pragma unroll
    for (int j = 0; j < L; ++j) {
      ushort4 hv = hp[j * 64];
      float h0 = bf2f(hv.x), h1 = bf2f(hv.y), h2 = bf2f(hv.z), h3 = bf2f(hv.w);
      float n0 = BETA * u[0] + f[0]; f[0] = ALPHA * f[0] + h0; u[0] = n0;
      float n1 = BETA * u[1] + f[1]; f[1] = ALPHA * f[1] + h1; u[1] = n1;
      float n2 = BETA * u[2] + f[2]; f[2] = ALPHA * f[2] + h2; u[2] = n2;
      float n3 = BETA * u[3] + f[3]; f[3] = ALPHA * f[3] + h3; u[3] = n3;
    }
#pragma unroll
    for (int i = 0; i < 4; ++i) St[c][ol * 4 + i] = make_float2(f[i], u[i]);
  }
  __syncthreads();

  // phase 2: combine across chunks, in place (St[c] becomes Init[c])
  if (tid < 64) {
    float f = 0.f, u = 0.f;
#pragma unroll
    for (int cc = 0; cc < C; ++cc) {
      float2 s = St[cc][tid];
      St[cc][tid] = make_float2(f, u);
      float nu = BL * u + WL * f + s.y;   // uses old f
      f = AL * f + s.x;
      u = nu;
    }
  }
  __syncthreads();

  // phase 3: final scan with chunk inits, write Out
  {
    float f[4], u[4];
#pragma unroll
    for (int i = 0; i < 4; ++i) { float2 s = St[c][ol * 4 + i]; f[i] = s.x; u[i] = s.y; }
    float4* op = (float4*)(Out + base);
#pragma unroll
    for (int j = 0; j < L; ++j) {
      ushort4 hv = hp[j * 64];
      float h0 = bf2f(hv.x), h1 = bf2f(hv.y), h2 = bf2f(hv.z), h3 = bf2f(hv.w);
      float4 o4;
      o4.x = BETA * u[0] + f[0]; f[0] = ALPHA * f[0] + h0; u[0] = o4.x;
      o4.y = BETA * u[1] + f[1]; f[1] = ALPHA * f[1] + h1; u[1] = o4.y;
      o4.z = BETA * u[2] + f[2]; f[2] = ALPHA * f[2] + h2; u[2] = o4.z;
      o4.w = BETA * u[3] + f[3]; f[3] = ALPHA * f[3] + h3; u[3] = o4.w;
      op[j * 64] = o4;
    }
  }
}

extern "C" void kernel_launch(void* const* d_in, const int* in_sizes, int n_in,
                              void* d_out, int out_size, void* d_ws, size_t ws_size,
                              hipStream_t stream) {
  const float* A = (const float*)d_in[0];   // (B, T, I) fp32
  const float* W = (const float*)d_in[1];   // (O, I) fp32
  float* Out = (float*)d_out;               // (B, T, O) fp32

  // workspace: H (bf16, 32.77MB) | Wbf (bf16, 0.25MB)
  uint16_t* H   = (uint16_t*)d_ws;
  uint16_t* Wbf = H + (size_t)M * Odim;

  wconv<<<Odim * Idim / (256 * 8), 256, 0, stream>>>(W, Wbf);
  gemm_h<<<M / 64, 256, 0, stream>>>(A, Wbf, H);
  scan_all<<<Bdim * 4, 640, 0, stream>>>(H, Out);
}